// Round 5
// baseline (649.978 us; speedup 1.0000x reference)
//
#include <hip/hip_runtime.h>
#include <math.h>

// ---------------------------------------------------------------------------
// Fastformer encoder layer — Round 5: barrier-free register-flat GEMMs.
//
// R4 post-mortem: MfmaUtil pinned at 27% by the per-stage barrier vmcnt(0)
// drain (load latency fully exposed, blocks convoy). R5 removes LDS and
// barriers from the GEMM K-loop: A and B fragments both load direct
// global->register, ping-pong double-buffered one k32 stage ahead. With no
// s_barrier the compiler emits fine-grained per-register s_waitcnt vmcnt(N)
// (AITER-style), loads stay in flight across stages. L1 absorbs twin-wave
// duplicate fragment lines; L2 serves the rest (<81% of 34.5 TB/s ceiling).
//
//  * TM=256 config: wave tile 128x64, acc 128 VGPR, 2 waves/SIMD.
//  * TM=128 config (small-N GEMMs): wave tile 64x64, acc 64, 3 waves/SIMD,
//    grids >= 512 blocks (2+ blocks/CU) to fix R4's 1-block/CU latency hole.
//  * LIN1ACT keeps the dual-half a*relu(g) fusion; LDS used ONLY in its
//    epilogue exchange (dynamic smem, 0 for other instances).
// ws: h16@0(16M) | kv16/act16@16M(32M overlay) | vq@48M(16M) |
//     weights@64M(18M) | gk@82M | attn partials@83M
// ---------------------------------------------------------------------------

#define DM     1024
#define FFH    2048
#define M_TOT  8192

typedef _Float16 f16x8 __attribute__((ext_vector_type(8)));
typedef float    f32x4 __attribute__((ext_vector_type(4)));

__device__ __forceinline__ unsigned short f2h(float x) {
    union { _Float16 h; unsigned short u; } c;
    c.h = (_Float16)x;
    return c.u;
}
__device__ __forceinline__ float h2f(unsigned short u) {
    union { unsigned short u; _Float16 h; } c;
    c.u = u;
    return (float)c.h;
}

// ---------------------------------------------------------------------------
// fused weight cast: all 4 weight matrices fp32 -> fp16 in one launch.
// ---------------------------------------------------------------------------
__global__ __launch_bounds__(256) void wcast_all(
    const float* __restrict__ s0, const float* __restrict__ s1,
    const float* __restrict__ s2, const float* __restrict__ s3,
    unsigned short* __restrict__ d0, unsigned short* __restrict__ d1,
    unsigned short* __restrict__ d2, unsigned short* __restrict__ d3)
{
    const int i = blockIdx.x * 256 + threadIdx.x;
    const float* s; unsigned short* d; int off;
    if      (i <  524288) { s = s0; d = d0; off = i; }
    else if (i <  786432) { s = s1; d = d1; off = i - 524288; }
    else if (i < 1835008) { s = s2; d = d2; off = i - 786432; }
    else                  { s = s3; d = d3; off = i - 1835008; }
    const float4 v = ((const float4*)s)[off];
    ushort4 h;
    h.x = f2h(v.x); h.y = f2h(v.y); h.z = f2h(v.z); h.w = f2h(v.w);
    ((ushort4*)d)[off] = h;
}

// ---------------------------------------------------------------------------
// LayerNorm -> fp16. One block/row, one float4/thread.
// ---------------------------------------------------------------------------
__global__ __launch_bounds__(256) void ln_f16(
    const float* __restrict__ x, const float* __restrict__ g,
    const float* __restrict__ b, unsigned short* __restrict__ y)
{
    const int row = blockIdx.x;
    const int t   = threadIdx.x;
    const float4 v = ((const float4*)(x + (size_t)row * DM))[t];

    float s  = v.x + v.y + v.z + v.w;
    float ss = v.x * v.x + v.y * v.y + v.z * v.z + v.w * v.w;
    #pragma unroll
    for (int off = 32; off > 0; off >>= 1) {
        s  += __shfl_xor(s, off);
        ss += __shfl_xor(ss, off);
    }
    __shared__ float sm[8];
    const int wave = t >> 6;
    if ((t & 63) == 0) { sm[wave * 2] = s; sm[wave * 2 + 1] = ss; }
    __syncthreads();
    s  = sm[0] + sm[2] + sm[4] + sm[6];
    ss = sm[1] + sm[3] + sm[5] + sm[7];

    const float mu  = s * (1.0f / DM);
    const float var = ss * (1.0f / DM) - mu * mu;
    const float r   = rsqrtf(var + 1e-5f);

    const float4 gv = ((const float4*)g)[t];
    const float4 bv = ((const float4*)b)[t];
    ushort4 o;
    o.x = f2h((v.x - mu) * r * gv.x + bv.x);
    o.y = f2h((v.y - mu) * r * gv.y + bv.y);
    o.z = f2h((v.z - mu) * r * gv.z + bv.z);
    o.w = f2h((v.w - mu) * r * gv.w + bv.w);
    ((ushort4*)(y + (size_t)row * DM))[t] = o;
}

// ---------------------------------------------------------------------------
// attention partial pass + merge (verified in R4).
// ---------------------------------------------------------------------------
__global__ __launch_bounds__(256) void attn_part(
    const unsigned short* __restrict__ kv, const float* __restrict__ kw,
    float* __restrict__ pm, float* __restrict__ pl, float* __restrict__ ps)
{
    const int blk = blockIdx.x;
    const int bh = blk >> 2, qt = blk & 3;
    const int b = bh >> 4, h = bh & 15;
    const int t = threadIdx.x, e = t & 63, w = t >> 6;
    const int nbase = qt * 256 + w * 64;
    const unsigned short* kp =
        kv + (size_t)b * 1024 * 2048 + (size_t)nbase * 2048 + h * 64 + e;
    const float* kwr = kw + h * 1024 + nbase;

    float m = -1e30f, l = 0.f, s = 0.f;
    #pragma unroll 4
    for (int i = 0; i < 64; ++i) {
        const float kval = h2f(kp[(size_t)i * 2048]);
        const float x    = kval * kwr[i] * 0.125f;
        const float nm   = fmaxf(m, x);
        const float c    = __expf(m - nm);
        const float ex   = __expf(x - nm);
        l = l * c + ex;
        s = s * c + ex * kval;
        m = nm;
    }
    __shared__ float sm[3][256];
    sm[0][t] = m; sm[1][t] = l; sm[2][t] = s;
    __syncthreads();
    if (t < 64) {
        #pragma unroll
        for (int ww = 1; ww < 4; ++ww) {
            const float m2 = sm[0][ww * 64 + e];
            const float l2 = sm[1][ww * 64 + e];
            const float s2 = sm[2][ww * 64 + e];
            const float nm = fmaxf(m, m2);
            const float c1 = __expf(m - nm);
            const float c2 = __expf(m2 - nm);
            l = l * c1 + l2 * c2;
            s = s * c1 + s2 * c2;
            m = nm;
        }
        const int o = blk * 64 + e;
        pm[o] = m; pl[o] = l; ps[o] = s;
    }
}

__global__ __launch_bounds__(64) void attn_merge(
    const float* __restrict__ pm, const float* __restrict__ pl,
    const float* __restrict__ ps, float* __restrict__ gk)
{
    const int bh = blockIdx.x, e = threadIdx.x;
    const int b = bh >> 4, h = bh & 15;
    int o = bh * 4 * 64 + e;
    float m = pm[o], l = pl[o], s = ps[o];
    #pragma unroll
    for (int qt = 1; qt < 4; ++qt) {
        o += 64;
        const float m2 = pm[o], l2 = pl[o], s2 = ps[o];
        const float nm = fmaxf(m, m2);
        const float c1 = __expf(m - nm);
        const float c2 = __expf(m2 - nm);
        l = l * c1 + l2 * c2;
        s = s * c1 + s2 * c2;
        m = nm;
    }
    gk[(size_t)b * DM + h * 64 + e] = s / l;
}

// ---------------------------------------------------------------------------
// v-scale: vq[m][d] = fp16( v16[m][d] * gk[batch][d] ).
// ---------------------------------------------------------------------------
__global__ __launch_bounds__(256) void vscale_f16(
    const unsigned short* __restrict__ kv, const float* __restrict__ gk,
    unsigned short* __restrict__ vq)
{
    const int m = blockIdx.x;
    const int t = threadIdx.x;
    const int b = m >> 10;
    const ushort4 v4 = *(const ushort4*)(kv + (size_t)m * 2048 + 1024 + t * 4);
    const float4  s4 = *(const float4*)(gk + b * DM + t * 4);
    ushort4 o;
    o.x = f2h(h2f(v4.x) * s4.x);
    o.y = f2h(h2f(v4.y) * s4.y);
    o.z = f2h(h2f(v4.z) * s4.z);
    o.w = f2h(h2f(v4.w) * s4.w);
    *(ushort4*)(vq + (size_t)m * DM + t * 4) = o;
}

// ---------------------------------------------------------------------------
// Barrier-free register-flat fp16 MFMA GEMM.
// C[M,N] = A[M,K] @ W[N,K]^T + bias (+res).  256 thr = 4 waves (wm x wn).
// TM=256: wave 128x64 (MF=8); TM=128: wave 64x64 (MF=4). Cols: 128
// (LIN1ACT: 64, wn selects a/g half of W). No LDS/barriers in K-loop; A and
// B frags direct global->reg, ping-pong dbuf one k32 stage ahead -> compiler
// emits fine-grained vmcnt(N). OUTM: 0 = fp16 out, 2 = fp32 out + residual.
// ---------------------------------------------------------------------------
template <int TM, bool LIN1ACT, int OUTM>
__global__ __launch_bounds__(256, (TM == 256 ? 2 : 3)) void fgemm(
    const unsigned short* __restrict__ A,
    const unsigned short* __restrict__ B,
    const float* __restrict__ bias,
    const float* __restrict__ residual,
    float* __restrict__ Cf, unsigned short* __restrict__ Cq,
    int K, int lda, int ldc)
{
    constexpr int MF = (TM == 256) ? 8 : 4;
    extern __shared__ unsigned short xch[];    // LIN1ACT epilogue only

    const int t  = threadIdx.x;
    const int m0 = blockIdx.y * TM;
    const int n0 = blockIdx.x * (LIN1ACT ? 64 : 128);
    const int L  = t & 63, w = t >> 6;
    const int wm = w >> 1, wn = w & 1;
    const int fr = L & 15, q = L >> 4;

    // per-fragment element offsets (ushort units), k added per stage
    unsigned aoff[MF], boff[4];
    #pragma unroll
    for (int mi = 0; mi < MF; ++mi) {
        const int row = m0 + wm * (TM / 2) + mi * 16 + fr;
        aoff[mi] = (unsigned)row * (unsigned)lda + q * 8;
    }
    #pragma unroll
    for (int ni = 0; ni < 4; ++ni) {
        const int brow = LIN1ACT ? ((wn ? FFH : 0) + n0 + ni * 16 + fr)
                                 : (n0 + wn * 64 + ni * 16 + fr);
        boff[ni] = (unsigned)brow * (unsigned)K + q * 8;
    }

    f32x4 acc[MF][4];
    #pragma unroll
    for (int i = 0; i < MF; ++i)
        #pragma unroll
        for (int j = 0; j < 4; ++j) acc[i][j] = (f32x4){0.f, 0.f, 0.f, 0.f};

    f16x8 a0[MF], b0[4], a1[MF], b1[4];
    #pragma unroll
    for (int mi = 0; mi < MF; ++mi) a0[mi] = *(const f16x8*)(A + aoff[mi]);
    #pragma unroll
    for (int ni = 0; ni < 4;  ++ni) b0[ni] = *(const f16x8*)(B + boff[ni]);

    for (int k = 0; k < K; k += 64) {
        // issue stage k+32 while computing stage k
        #pragma unroll
        for (int mi = 0; mi < MF; ++mi)
            a1[mi] = *(const f16x8*)(A + aoff[mi] + k + 32);
        #pragma unroll
        for (int ni = 0; ni < 4; ++ni)
            b1[ni] = *(const f16x8*)(B + boff[ni] + k + 32);
        #pragma unroll
        for (int mi = 0; mi < MF; ++mi)
            #pragma unroll
            for (int ni = 0; ni < 4; ++ni)
                acc[mi][ni] = __builtin_amdgcn_mfma_f32_16x16x32_f16(
                    a0[mi], b0[ni], acc[mi][ni], 0, 0, 0);

        const int k2 = (k + 64 < K) ? k + 64 : 0;   // tail: benign re-read
        #pragma unroll
        for (int mi = 0; mi < MF; ++mi)
            a0[mi] = *(const f16x8*)(A + aoff[mi] + k2);
        #pragma unroll
        for (int ni = 0; ni < 4; ++ni)
            b0[ni] = *(const f16x8*)(B + boff[ni] + k2);
        #pragma unroll
        for (int mi = 0; mi < MF; ++mi)
            #pragma unroll
            for (int ni = 0; ni < 4; ++ni)
                acc[mi][ni] = __builtin_amdgcn_mfma_f32_16x16x32_f16(
                    a1[mi], b1[ni], acc[mi][ni], 0, 0, 0);
    }

    if (!LIN1ACT) {
        float bc[4];
        #pragma unroll
        for (int ni = 0; ni < 4; ++ni)
            bc[ni] = bias[n0 + wn * 64 + ni * 16 + fr];
        #pragma unroll
        for (int mi = 0; mi < MF; ++mi)
            #pragma unroll
            for (int ni = 0; ni < 4; ++ni) {
                const int gcol = n0 + wn * 64 + ni * 16 + fr;
                #pragma unroll
                for (int r = 0; r < 4; ++r) {
                    const int grow = m0 + wm * (TM / 2) + mi * 16 + q * 4 + r;
                    float v = acc[mi][ni][r] + bc[ni];
                    if (OUTM == 2) {
                        v += residual[(size_t)grow * ldc + gcol];
                        Cf[(size_t)grow * ldc + gcol] = v;
                    } else {
                        Cq[(size_t)grow * ldc + gcol] = f2h(v);
                    }
                }
            }
    } else {
        // a*relu(g) cross-wave exchange through (dynamic) LDS
        if (wn == 1) {
            #pragma unroll
            for (int mi = 0; mi < MF; ++mi)
                #pragma unroll
                for (int ni = 0; ni < 4; ++ni) {
                    const int col = ni * 16 + fr;
                    const float bg = bias[FFH + n0 + col];
                    #pragma unroll
                    for (int r = 0; r < 4; ++r) {
                        const int row = wm * (TM / 2) + mi * 16 + q * 4 + r;
                        xch[row * 72 + col] =
                            f2h(fmaxf(acc[mi][ni][r] + bg, 0.f));
                    }
                }
        }
        __syncthreads();
        if (wn == 0) {
            #pragma unroll
            for (int mi = 0; mi < MF; ++mi)
                #pragma unroll
                for (int ni = 0; ni < 4; ++ni) {
                    const int col = ni * 16 + fr;
                    const float ba = bias[n0 + col];
                    #pragma unroll
                    for (int r = 0; r < 4; ++r) {
                        const int row = wm * (TM / 2) + mi * 16 + q * 4 + r;
                        const float a = acc[mi][ni][r] + ba;
                        const float o = a * h2f(xch[row * 72 + col]);
                        Cq[(size_t)(m0 + row) * FFH + n0 + col] = f2h(o);
                    }
                }
        }
    }
}

// ---------------------------------------------------------------------------
extern "C" void kernel_launch(void* const* d_in, const int* in_sizes, int n_in,
                              void* d_out, int out_size, void* d_ws, size_t ws_size,
                              hipStream_t stream)
{
    const float* hidden = (const float*)d_in[0];
    const float* qkv_w  = (const float*)d_in[2];
    const float* qkv_b  = (const float*)d_in[3];
    const float* out_w  = (const float*)d_in[4];
    const float* out_b  = (const float*)d_in[5];
    const float* key_w  = (const float*)d_in[7];
    const float* n1g    = (const float*)d_in[8];
    const float* n1b    = (const float*)d_in[9];
    const float* n2g    = (const float*)d_in[10];
    const float* n2b    = (const float*)d_in[11];
    const float* l1w    = (const float*)d_in[12];
    const float* l1b    = (const float*)d_in[13];
    const float* l2w    = (const float*)d_in[14];
    const float* l2b    = (const float*)d_in[15];
    float* out = (float*)d_out;
    char*  wsb = (char*)d_ws;

    const size_t MB = 1u << 20;
    unsigned short* h16   = (unsigned short*)wsb;               // 16 MB
    unsigned short* kv16  = (unsigned short*)(wsb + 16 * MB);   // 32 MB
    unsigned short* act16 = (unsigned short*)(wsb + 16 * MB);   // overlay
    unsigned short* vq    = (unsigned short*)(wsb + 48 * MB);   // 16 MB
    unsigned short* wkv16 = (unsigned short*)(wsb + 64 * MB);   // 4 MB
    unsigned short* wo16  = (unsigned short*)(wsb + 68 * MB);   // 2 MB
    unsigned short* wl116 = (unsigned short*)(wsb + 70 * MB);   // 8 MB
    unsigned short* wl216 = (unsigned short*)(wsb + 78 * MB);   // 4 MB
    float*          gk    = (float*)(wsb + 82 * MB);            // 32 KB
    float*          pm    = (float*)(wsb + 83 * MB);            // 128 KB
    float*          pl    = (float*)(wsb + 83 * MB + 131072);
    float*          ps    = (float*)(wsb + 83 * MB + 262144);

    // 0. weights fp32 -> fp16
    wcast_all<<<9216, 256, 0, stream>>>(
        qkv_w + (size_t)DM * DM, out_w, l1w, l2w,
        wkv16, wo16, wl116, wl216);

    // 1. h1 = LN1(hidden) -> fp16
    ln_f16<<<M_TOT, 256, 0, stream>>>(hidden, n1g, n1b, h16);

    // 2. kv16 = fp16( h1 @ Wkv^T + b )   (ldc 2048), grid 512 = 2/CU
    fgemm<256, false, 0><<<dim3(16, 32), 256, 0, stream>>>(
        h16, wkv16, qkv_b + DM, nullptr, nullptr, kv16, 1024, 1024, 2048);

    // 3. global_key (partial + merge)
    attn_part<<<512, 256, 0, stream>>>(kv16, key_w, pm, pl, ps);
    attn_merge<<<128, 64, 0, stream>>>(pm, pl, ps, gk);

    // 4. vq = fp16(v * gk)
    vscale_f16<<<M_TOT, 256, 0, stream>>>(kv16, gk, vq);

    // 5. hidden2 = hidden + vq @ out_w^T + out_b  -> d_out, grid 512
    fgemm<128, false, 2><<<dim3(8, 64), 256, 0, stream>>>(
        vq, wo16, out_b, hidden, out, nullptr, 1024, 1024, 1024);

    // 6. h2 = LN2(hidden2) -> fp16
    ln_f16<<<M_TOT, 256, 0, stream>>>(out, n2g, n2b, h16);

    // 7. act16 = fp16( (h2@W_a^T + b_a) * relu(h2@W_g^T + b_g) ), grid 1024
    fgemm<256, true, 0><<<dim3(32, 32), 256, 256 * 72 * 2, stream>>>(
        h16, wl116, l1b, nullptr, nullptr, act16, 1024, 1024, 0);

    // 8. out = hidden2 + act @ l2w^T + l2b  (in-place residual), grid 512
    fgemm<128, false, 2><<<dim3(8, 64), 256, 0, stream>>>(
        act16, wl216, l2b, out, out, nullptr, 2048, 2048, 1024);
}

// Round 6
// 379.209 us; speedup vs baseline: 1.7140x; 1.7140x over previous
//
#include <hip/hip_runtime.h>
#include <math.h>

// ---------------------------------------------------------------------------
// Fastformer encoder layer — Round 6: swizzled-B direct + LDS-dbuf A GEMMs.
//
// R5 post-mortem: per-lane fragment loads from row-major W are address-
// divergent (16 lines per instr) -> TA/L1-bound, MfmaUtil 14%. R6:
//  * Weights pre-swizzled to MFMA fragment-linear layout (wcast_sw): a
//    B-frag load is base+lane*16B -> coalesced direct-to-reg, no LDS, no
//    barrier; reg ping-pong dbuf.
//  * A staged via coalesced global_load_lds, NOW double-buffered (R4's
//    single buffer exposed full load latency at every barrier).
//  * Block tile 256x256 (512 thr, 8 waves, wave 128x64): per-iter unique
//    bytes 64KB/8.4MFLOP -> ~10 TB/s L2 demand at peak (under ceiling);
//    LDS reads A-only (0.75 util). Small-N GEMMs: 256x128 variant.
// ws: h16@0(16M) | kv16/act16@16M(32M overlay) | vq@48M(16M) |
//     swizzled weights@64M(18M) | gk@82M | attn partials@83M
// ---------------------------------------------------------------------------

#define DM     1024
#define FFH    2048
#define M_TOT  8192

typedef _Float16 f16x8 __attribute__((ext_vector_type(8)));
typedef float    f32x4 __attribute__((ext_vector_type(4)));

__device__ __forceinline__ void gl2lds16(const void* g, void* l) {
    __builtin_amdgcn_global_load_lds(
        (const __attribute__((address_space(1))) void*)g,
        (__attribute__((address_space(3))) void*)l, 16, 0, 0);
}
__device__ __forceinline__ unsigned short f2h(float x) {
    union { _Float16 h; unsigned short u; } c;
    c.h = (_Float16)x;
    return c.u;
}
__device__ __forceinline__ float h2f(unsigned short u) {
    union { unsigned short u; _Float16 h; } c;
    c.u = u;
    return (float)c.h;
}

// ---------------------------------------------------------------------------
// weight cast fp32 -> fp16 in fragment-linear layout:
// chunk id i = (ntile*KT + kt)*64 + lane ; chunk holds
// W[ntile*16 + (lane&15)][kt*32 + (lane>>4)*8 .. +8].  16B store per thread.
// ---------------------------------------------------------------------------
__global__ __launch_bounds__(256) void wcast_sw(
    const float* __restrict__ s0, const float* __restrict__ s1,
    const float* __restrict__ s2, const float* __restrict__ s3,
    unsigned short* __restrict__ d0, unsigned short* __restrict__ d1,
    unsigned short* __restrict__ d2, unsigned short* __restrict__ d3)
{
    int i = blockIdx.x * 256 + threadIdx.x;
    const float* s; unsigned short* d; int ks;
    if      (i < 262144) {               s = s0; d = d0; ks = 5; }
    else if (i < 393216) { i -= 262144;  s = s1; d = d1; ks = 5; }
    else if (i < 917504) { i -= 393216;  s = s2; d = d2; ks = 5; }
    else                 { i -= 917504;  s = s3; d = d3; ks = 6; }
    const int lane = i & 63, tile = i >> 6;
    const int kt = tile & ((1 << ks) - 1), nt = tile >> ks;
    const int fr = lane & 15, qq = lane >> 4;
    const int K = 32 << ks;
    const float* src = s + (size_t)(nt * 16 + fr) * K + kt * 32 + qq * 8;
    const float4 v0 = ((const float4*)src)[0];
    const float4 v1 = ((const float4*)src)[1];
    ushort4 h0, h1;
    h0.x = f2h(v0.x); h0.y = f2h(v0.y); h0.z = f2h(v0.z); h0.w = f2h(v0.w);
    h1.x = f2h(v1.x); h1.y = f2h(v1.y); h1.z = f2h(v1.z); h1.w = f2h(v1.w);
    unsigned short* dst = d + (size_t)i * 8;
    *(ushort4*)dst       = h0;
    *(ushort4*)(dst + 4) = h1;
}

// ---------------------------------------------------------------------------
// LayerNorm -> fp16. One block/row, one float4/thread.
// ---------------------------------------------------------------------------
__global__ __launch_bounds__(256) void ln_f16(
    const float* __restrict__ x, const float* __restrict__ g,
    const float* __restrict__ b, unsigned short* __restrict__ y)
{
    const int row = blockIdx.x;
    const int t   = threadIdx.x;
    const float4 v = ((const float4*)(x + (size_t)row * DM))[t];

    float s  = v.x + v.y + v.z + v.w;
    float ss = v.x * v.x + v.y * v.y + v.z * v.z + v.w * v.w;
    #pragma unroll
    for (int off = 32; off > 0; off >>= 1) {
        s  += __shfl_xor(s, off);
        ss += __shfl_xor(ss, off);
    }
    __shared__ float sm[8];
    const int wave = t >> 6;
    if ((t & 63) == 0) { sm[wave * 2] = s; sm[wave * 2 + 1] = ss; }
    __syncthreads();
    s  = sm[0] + sm[2] + sm[4] + sm[6];
    ss = sm[1] + sm[3] + sm[5] + sm[7];

    const float mu  = s * (1.0f / DM);
    const float var = ss * (1.0f / DM) - mu * mu;
    const float r   = rsqrtf(var + 1e-5f);

    const float4 gv = ((const float4*)g)[t];
    const float4 bv = ((const float4*)b)[t];
    ushort4 o;
    o.x = f2h((v.x - mu) * r * gv.x + bv.x);
    o.y = f2h((v.y - mu) * r * gv.y + bv.y);
    o.z = f2h((v.z - mu) * r * gv.z + bv.z);
    o.w = f2h((v.w - mu) * r * gv.w + bv.w);
    ((ushort4*)(y + (size_t)row * DM))[t] = o;
}

// ---------------------------------------------------------------------------
// attention partial pass + merge (verified R4/R5).
// ---------------------------------------------------------------------------
__global__ __launch_bounds__(256) void attn_part(
    const unsigned short* __restrict__ kv, const float* __restrict__ kw,
    float* __restrict__ pm, float* __restrict__ pl, float* __restrict__ ps)
{
    const int blk = blockIdx.x;
    const int bh = blk >> 2, qt = blk & 3;
    const int b = bh >> 4, h = bh & 15;
    const int t = threadIdx.x, e = t & 63, w = t >> 6;
    const int nbase = qt * 256 + w * 64;
    const unsigned short* kp =
        kv + (size_t)b * 1024 * 2048 + (size_t)nbase * 2048 + h * 64 + e;
    const float* kwr = kw + h * 1024 + nbase;

    float m = -1e30f, l = 0.f, s = 0.f;
    #pragma unroll 4
    for (int i = 0; i < 64; ++i) {
        const float kval = h2f(kp[(size_t)i * 2048]);
        const float x    = kval * kwr[i] * 0.125f;
        const float nm   = fmaxf(m, x);
        const float c    = __expf(m - nm);
        const float ex   = __expf(x - nm);
        l = l * c + ex;
        s = s * c + ex * kval;
        m = nm;
    }
    __shared__ float sm[3][256];
    sm[0][t] = m; sm[1][t] = l; sm[2][t] = s;
    __syncthreads();
    if (t < 64) {
        #pragma unroll
        for (int ww = 1; ww < 4; ++ww) {
            const float m2 = sm[0][ww * 64 + e];
            const float l2 = sm[1][ww * 64 + e];
            const float s2 = sm[2][ww * 64 + e];
            const float nm = fmaxf(m, m2);
            const float c1 = __expf(m - nm);
            const float c2 = __expf(m2 - nm);
            l = l * c1 + l2 * c2;
            s = s * c1 + s2 * c2;
            m = nm;
        }
        const int o = blk * 64 + e;
        pm[o] = m; pl[o] = l; ps[o] = s;
    }
}

__global__ __launch_bounds__(64) void attn_merge(
    const float* __restrict__ pm, const float* __restrict__ pl,
    const float* __restrict__ ps, float* __restrict__ gk)
{
    const int bh = blockIdx.x, e = threadIdx.x;
    const int b = bh >> 4, h = bh & 15;
    int o = bh * 4 * 64 + e;
    float m = pm[o], l = pl[o], s = ps[o];
    #pragma unroll
    for (int qt = 1; qt < 4; ++qt) {
        o += 64;
        const float m2 = pm[o], l2 = pl[o], s2 = ps[o];
        const float nm = fmaxf(m, m2);
        const float c1 = __expf(m - nm);
        const float c2 = __expf(m2 - nm);
        l = l * c1 + l2 * c2;
        s = s * c1 + s2 * c2;
        m = nm;
    }
    gk[(size_t)b * DM + h * 64 + e] = s / l;
}

// ---------------------------------------------------------------------------
// v-scale: vq[m][d] = fp16( v16[m][d] * gk[batch][d] ).
// ---------------------------------------------------------------------------
__global__ __launch_bounds__(256) void vscale_f16(
    const unsigned short* __restrict__ kv, const float* __restrict__ gk,
    unsigned short* __restrict__ vq)
{
    const int m = blockIdx.x;
    const int t = threadIdx.x;
    const int b = m >> 10;
    const ushort4 v4 = *(const ushort4*)(kv + (size_t)m * 2048 + 1024 + t * 4);
    const float4  s4 = *(const float4*)(gk + b * DM + t * 4);
    ushort4 o;
    o.x = f2h(h2f(v4.x) * s4.x);
    o.y = f2h(h2f(v4.y) * s4.y);
    o.z = f2h(h2f(v4.z) * s4.z);
    o.w = f2h(h2f(v4.w) * s4.w);
    *(ushort4*)(vq + (size_t)m * DM + t * 4) = o;
}

// ---------------------------------------------------------------------------
// fp16 MFMA GEMM: 512 thr = 8 waves, block tile 256 x BN.
// BN=256: waves 2x4, wave 128x64 (MF=8).  BN=128: waves 4x2, wave 64x64.
// A: global_load_lds staging, 2x32KB double-buffered, XOR-swizzled rows.
// B: fragment-linear swizzled weights, coalesced direct-to-reg, reg dbuf.
// LIN1ACT (BN=256): wn<2 = a-half cols, wn>=2 = g-half; a*relu(g) via
// 64KB LDS exchange after the K-loop.  OUTM: 0 fp16 out, 2 fp32 + residual.
// ---------------------------------------------------------------------------
template <int BN, bool LIN1ACT, int OUTM>
__global__ __launch_bounds__(512, 2) void fgemm(
    const unsigned short* __restrict__ A,
    const unsigned short* __restrict__ Bsw,
    const float* __restrict__ bias,
    const float* __restrict__ residual,
    float* __restrict__ Cf, unsigned short* __restrict__ Cq,
    int K, int lda, int ldc)
{
    constexpr int NWM   = (BN == 256) ? 2 : 4;
    constexpr int WROWS = 256 / NWM;          // 128 or 64
    constexpr int MF    = WROWS / 16;         // 8 or 4
    __shared__ __align__(16) char lds[65536]; // 2x32KB stages / 64KB xch

    const int t  = threadIdx.x;
    const int m0 = blockIdx.y * 256;
    const int n0 = blockIdx.x * (LIN1ACT ? 128 : BN);
    const int L  = t & 63, w = t >> 6;
    const int wm = (BN == 256) ? (w >> 2) : (w >> 1);
    const int wn = (BN == 256) ? (w & 3)  : (w & 1);
    const int fr = L & 15, q = L >> 4;
    const int KT = K >> 5;

    // A staging: 2048 chunks/stage, 4 per thread; c = t + j*512,
    // row = c>>3, chunk-in-row = (c&7)^(row&7).
    const int arow = t >> 3;
    const int ach  = (t & 7) ^ (arow & 7);
    const unsigned short* pA0 = A + (size_t)(m0 + arow) * lda + ach * 8;
    const int ldst0 = t * 16;

    // B fragment-linear base for this wave's 64-col slice.
    const int bcol0 = LIN1ACT ? ((wn >= 2 ? FFH : 0) + n0 + (wn & 1) * 64)
                              : (n0 + wn * 64);
    const unsigned short* pB = Bsw + (size_t)(bcol0 >> 4) * KT * 512 + L * 8;

    int aoff[MF];
    #pragma unroll
    for (int mi = 0; mi < MF; ++mi) {
        const int row = wm * WROWS + mi * 16 + fr;
        aoff[mi] = row * 128 + ((q ^ (row & 7)) * 16);
    }

    f32x4 acc[MF][4];
    #pragma unroll
    for (int i = 0; i < MF; ++i)
        #pragma unroll
        for (int j = 0; j < 4; ++j) acc[i][j] = (f32x4){0.f, 0.f, 0.f, 0.f};

    // prologue: stage 0 into buf0, B ktile 0 into b0
    #pragma unroll
    for (int j = 0; j < 4; ++j)
        gl2lds16(pA0 + (size_t)j * 64 * lda, lds + ldst0 + j * 8192);
    f16x8 b0[4], b1[4];
    #pragma unroll
    for (int ni = 0; ni < 4; ++ni)
        b0[ni] = *(const f16x8*)(pB + (size_t)ni * KT * 512);
    __syncthreads();

    int p = 0;
    for (int k0 = 0; k0 < K; k0 += 64) {
        const int ktn  = k0 >> 5;
        const int kpre = (k0 + 64 < K) ? k0 + 64 : 0;
        #pragma unroll
        for (int j = 0; j < 4; ++j)
            gl2lds16(pA0 + (size_t)j * 64 * lda + kpre,
                     lds + (p ^ 1) * 32768 + ldst0 + j * 8192);
        #pragma unroll
        for (int ni = 0; ni < 4; ++ni)
            b1[ni] = *(const f16x8*)(pB + ((size_t)ni * KT + ktn + 1) * 512);

        f16x8 af[MF];
        #pragma unroll
        for (int mi = 0; mi < MF; ++mi)
            af[mi] = *(const f16x8*)(lds + p * 32768 + aoff[mi]);
        #pragma unroll
        for (int mi = 0; mi < MF; ++mi)
            #pragma unroll
            for (int ni = 0; ni < 4; ++ni)
                acc[mi][ni] = __builtin_amdgcn_mfma_f32_16x16x32_f16(
                    af[mi], b0[ni], acc[mi][ni], 0, 0, 0);

        const int kt2 = (ktn + 2 < KT) ? ktn + 2 : 0;
        #pragma unroll
        for (int ni = 0; ni < 4; ++ni)
            b0[ni] = *(const f16x8*)(pB + ((size_t)ni * KT + kt2) * 512);

        #pragma unroll
        for (int mi = 0; mi < MF; ++mi)
            af[mi] = *(const f16x8*)(lds + p * 32768 + (aoff[mi] ^ 64));
        #pragma unroll
        for (int mi = 0; mi < MF; ++mi)
            #pragma unroll
            for (int ni = 0; ni < 4; ++ni)
                acc[mi][ni] = __builtin_amdgcn_mfma_f32_16x16x32_f16(
                    af[mi], b1[ni], acc[mi][ni], 0, 0, 0);

        __syncthreads();
        p ^= 1;
    }

    if (!LIN1ACT) {
        float bc[4];
        #pragma unroll
        for (int ni = 0; ni < 4; ++ni)
            bc[ni] = bias[n0 + wn * 64 + ni * 16 + fr];
        #pragma unroll
        for (int mi = 0; mi < MF; ++mi)
            #pragma unroll
            for (int ni = 0; ni < 4; ++ni) {
                const int gcol = n0 + wn * 64 + ni * 16 + fr;
                #pragma unroll
                for (int r = 0; r < 4; ++r) {
                    const int grow = m0 + wm * WROWS + mi * 16 + q * 4 + r;
                    float v = acc[mi][ni][r] + bc[ni];
                    if (OUTM == 2) {
                        v += residual[(size_t)grow * ldc + gcol];
                        Cf[(size_t)grow * ldc + gcol] = v;
                    } else {
                        Cq[(size_t)grow * ldc + gcol] = f2h(v);
                    }
                }
            }
    } else {
        unsigned short* xch = (unsigned short*)lds;   // [256][128] fp16
        if (wn >= 2) {
            #pragma unroll
            for (int mi = 0; mi < MF; ++mi)
                #pragma unroll
                for (int ni = 0; ni < 4; ++ni) {
                    const int col = (wn - 2) * 64 + ni * 16 + fr;
                    const float bg = bias[FFH + n0 + col];
                    #pragma unroll
                    for (int r = 0; r < 4; ++r) {
                        const int row = wm * WROWS + mi * 16 + q * 4 + r;
                        xch[row * 128 + col] =
                            f2h(fmaxf(acc[mi][ni][r] + bg, 0.f));
                    }
                }
        }
        __syncthreads();
        if (wn < 2) {
            #pragma unroll
            for (int mi = 0; mi < MF; ++mi)
                #pragma unroll
                for (int ni = 0; ni < 4; ++ni) {
                    const int col = wn * 64 + ni * 16 + fr;
                    const float ba = bias[n0 + col];
                    #pragma unroll
                    for (int r = 0; r < 4; ++r) {
                        const int row = wm * WROWS + mi * 16 + q * 4 + r;
                        const float a = acc[mi][ni][r] + ba;
                        const float o = a * h2f(xch[row * 128 + col]);
                        Cq[(size_t)(m0 + row) * FFH + n0 + col] = f2h(o);
                    }
                }
        }
    }
}

// ---------------------------------------------------------------------------
extern "C" void kernel_launch(void* const* d_in, const int* in_sizes, int n_in,
                              void* d_out, int out_size, void* d_ws, size_t ws_size,
                              hipStream_t stream)
{
    const float* hidden = (const float*)d_in[0];
    const float* qkv_w  = (const float*)d_in[2];
    const float* qkv_b  = (const float*)d_in[3];
    const float* out_w  = (const float*)d_in[4];
    const float* out_b  = (const float*)d_in[5];
    const float* key_w  = (const float*)d_in[7];
    const float* n1g    = (const float*)d_in[8];
    const float* n1b    = (const float*)d_in[9];
    const float* n2g    = (const float*)d_in[10];
    const float* n2b    = (const float*)d_in[11];
    const float* l1w    = (const float*)d_in[12];
    const float* l1b    = (const float*)d_in[13];
    const float* l2w    = (const float*)d_in[14];
    const float* l2b    = (const float*)d_in[15];
    float* out = (float*)d_out;
    char*  wsb = (char*)d_ws;

    const size_t MB = 1u << 20;
    unsigned short* h16    = (unsigned short*)wsb;               // 16 MB
    unsigned short* kv16   = (unsigned short*)(wsb + 16 * MB);   // 32 MB
    unsigned short* act16  = (unsigned short*)(wsb + 16 * MB);   // overlay
    unsigned short* vq     = (unsigned short*)(wsb + 48 * MB);   // 16 MB
    unsigned short* wkv_sw = (unsigned short*)(wsb + 64 * MB);   // 4 MB
    unsigned short* wo_sw  = (unsigned short*)(wsb + 68 * MB);   // 2 MB
    unsigned short* l1_sw  = (unsigned short*)(wsb + 70 * MB);   // 8 MB
    unsigned short* l2_sw  = (unsigned short*)(wsb + 78 * MB);   // 4 MB
    float*          gk     = (float*)(wsb + 82 * MB);            // 32 KB
    float*          pm     = (float*)(wsb + 83 * MB);            // 128 KB
    float*          pl     = (float*)(wsb + 83 * MB + 131072);
    float*          ps     = (float*)(wsb + 83 * MB + 262144);

    // 0. weights -> fp16 fragment-linear layout
    wcast_sw<<<4608, 256, 0, stream>>>(
        qkv_w + (size_t)DM * DM, out_w, l1w, l2w,
        wkv_sw, wo_sw, l1_sw, l2_sw);

    // 1. h1 = LN1(hidden) -> fp16
    ln_f16<<<M_TOT, 256, 0, stream>>>(hidden, n1g, n1b, h16);

    // 2. kv16 = fp16( h1 @ Wkv^T + b )  (ldc 2048), 256 blocks
    fgemm<256, false, 0><<<dim3(8, 32), 512, 0, stream>>>(
        h16, wkv_sw, qkv_b + DM, nullptr, nullptr, kv16, 1024, 1024, 2048);

    // 3. global_key (partial + merge)
    attn_part<<<512, 256, 0, stream>>>(kv16, key_w, pm, pl, ps);
    attn_merge<<<128, 64, 0, stream>>>(pm, pl, ps, gk);

    // 4. vq = fp16(v * gk)
    vscale_f16<<<M_TOT, 256, 0, stream>>>(kv16, gk, vq);

    // 5. hidden2 = hidden + vq @ out_w^T + out_b -> d_out, 256 blocks
    fgemm<128, false, 2><<<dim3(8, 32), 512, 0, stream>>>(
        vq, wo_sw, out_b, hidden, out, nullptr, 1024, 1024, 1024);

    // 6. h2 = LN2(hidden2) -> fp16
    ln_f16<<<M_TOT, 256, 0, stream>>>(out, n2g, n2b, h16);

    // 7. act16 = fp16( (h2@W_a^T+b_a) * relu(h2@W_g^T+b_g) ), 512 blocks
    fgemm<256, true, 0><<<dim3(16, 32), 512, 0, stream>>>(
        h16, l1_sw, l1b, nullptr, nullptr, act16, 1024, 1024, 0);

    // 8. out = hidden2 + act @ l2w^T + l2b (in-place residual), 256 blocks
    fgemm<128, false, 2><<<dim3(8, 32), 512, 0, stream>>>(
        act16, l2_sw, l2b, out, out, nullptr, 2048, 2048, 1024);
}

// Round 7
// 370.179 us; speedup vs baseline: 1.7558x; 1.0244x over previous
//
#include <hip/hip_runtime.h>
#include <math.h>

// ---------------------------------------------------------------------------
// Fastformer encoder layer — Round 7: lean blocks for 3-blocks/CU residency.
//
// R6 post-mortem: 512-thr blocks with 128-AGPR accumulators (hidden from
// VGPR_Count) -> 224 regs/wave -> 1 block/CU -> nothing hides the barrier
// drain -> MfmaUtil capped 35%. Fragment-BW roofline (~95 B/cyc/CU at full
// MFMA rate for 64x64 wave tiles) is NOT the cap. R7 keeps the validated
// swizzled-B direct-to-reg + A global_load_lds-dbuf pipe, but:
//  * block 256 thr = 4 waves (2x2), tile 128x128, wave 64x64 (acc 64 AGPR,
//    ~150 unified regs, __launch_bounds__(256,3)) -> 3 blocks/CU.
//  * LDS 32 KB: 2x16KB A stages (dbuf); LIN1ACT xch (16KB) reuses it.
//  * All grids >= 512 blocks (>=2/CU).
// ws: h16@0(16M) | kv16/act16@16M(32M overlay) | vq@48M(16M) |
//     swizzled weights@64M(18M) | gk@82M | attn partials@83M
// ---------------------------------------------------------------------------

#define DM     1024
#define FFH    2048
#define M_TOT  8192

typedef _Float16 f16x8 __attribute__((ext_vector_type(8)));
typedef float    f32x4 __attribute__((ext_vector_type(4)));

__device__ __forceinline__ void gl2lds16(const void* g, void* l) {
    __builtin_amdgcn_global_load_lds(
        (const __attribute__((address_space(1))) void*)g,
        (__attribute__((address_space(3))) void*)l, 16, 0, 0);
}
__device__ __forceinline__ unsigned short f2h(float x) {
    union { _Float16 h; unsigned short u; } c;
    c.h = (_Float16)x;
    return c.u;
}
__device__ __forceinline__ float h2f(unsigned short u) {
    union { unsigned short u; _Float16 h; } c;
    c.u = u;
    return (float)c.h;
}

// ---------------------------------------------------------------------------
// weight cast fp32 -> fp16 in fragment-linear layout (validated R6):
// chunk i = (ntile*KT + kt)*64 + lane ; holds
// W[nt*16 + (lane&15)][kt*32 + (lane>>4)*8 .. +8].
// ---------------------------------------------------------------------------
__global__ __launch_bounds__(256) void wcast_sw(
    const float* __restrict__ s0, const float* __restrict__ s1,
    const float* __restrict__ s2, const float* __restrict__ s3,
    unsigned short* __restrict__ d0, unsigned short* __restrict__ d1,
    unsigned short* __restrict__ d2, unsigned short* __restrict__ d3)
{
    int i = blockIdx.x * 256 + threadIdx.x;
    const float* s; unsigned short* d; int ks;
    if      (i < 262144) {               s = s0; d = d0; ks = 5; }
    else if (i < 393216) { i -= 262144;  s = s1; d = d1; ks = 5; }
    else if (i < 917504) { i -= 393216;  s = s2; d = d2; ks = 5; }
    else                 { i -= 917504;  s = s3; d = d3; ks = 6; }
    const int lane = i & 63, tile = i >> 6;
    const int kt = tile & ((1 << ks) - 1), nt = tile >> ks;
    const int fr = lane & 15, qq = lane >> 4;
    const int K = 32 << ks;
    const float* src = s + (size_t)(nt * 16 + fr) * K + kt * 32 + qq * 8;
    const float4 v0 = ((const float4*)src)[0];
    const float4 v1 = ((const float4*)src)[1];
    ushort4 h0, h1;
    h0.x = f2h(v0.x); h0.y = f2h(v0.y); h0.z = f2h(v0.z); h0.w = f2h(v0.w);
    h1.x = f2h(v1.x); h1.y = f2h(v1.y); h1.z = f2h(v1.z); h1.w = f2h(v1.w);
    unsigned short* dst = d + (size_t)i * 8;
    *(ushort4*)dst       = h0;
    *(ushort4*)(dst + 4) = h1;
}

// ---------------------------------------------------------------------------
// LayerNorm -> fp16. One block/row, one float4/thread.
// ---------------------------------------------------------------------------
__global__ __launch_bounds__(256) void ln_f16(
    const float* __restrict__ x, const float* __restrict__ g,
    const float* __restrict__ b, unsigned short* __restrict__ y)
{
    const int row = blockIdx.x;
    const int t   = threadIdx.x;
    const float4 v = ((const float4*)(x + (size_t)row * DM))[t];

    float s  = v.x + v.y + v.z + v.w;
    float ss = v.x * v.x + v.y * v.y + v.z * v.z + v.w * v.w;
    #pragma unroll
    for (int off = 32; off > 0; off >>= 1) {
        s  += __shfl_xor(s, off);
        ss += __shfl_xor(ss, off);
    }
    __shared__ float sm[8];
    const int wave = t >> 6;
    if ((t & 63) == 0) { sm[wave * 2] = s; sm[wave * 2 + 1] = ss; }
    __syncthreads();
    s  = sm[0] + sm[2] + sm[4] + sm[6];
    ss = sm[1] + sm[3] + sm[5] + sm[7];

    const float mu  = s * (1.0f / DM);
    const float var = ss * (1.0f / DM) - mu * mu;
    const float r   = rsqrtf(var + 1e-5f);

    const float4 gv = ((const float4*)g)[t];
    const float4 bv = ((const float4*)b)[t];
    ushort4 o;
    o.x = f2h((v.x - mu) * r * gv.x + bv.x);
    o.y = f2h((v.y - mu) * r * gv.y + bv.y);
    o.z = f2h((v.z - mu) * r * gv.z + bv.z);
    o.w = f2h((v.w - mu) * r * gv.w + bv.w);
    ((ushort4*)(y + (size_t)row * DM))[t] = o;
}

// ---------------------------------------------------------------------------
// attention partial pass + merge (verified R4-R6).
// ---------------------------------------------------------------------------
__global__ __launch_bounds__(256) void attn_part(
    const unsigned short* __restrict__ kv, const float* __restrict__ kw,
    float* __restrict__ pm, float* __restrict__ pl, float* __restrict__ ps)
{
    const int blk = blockIdx.x;
    const int bh = blk >> 2, qt = blk & 3;
    const int b = bh >> 4, h = bh & 15;
    const int t = threadIdx.x, e = t & 63, w = t >> 6;
    const int nbase = qt * 256 + w * 64;
    const unsigned short* kp =
        kv + (size_t)b * 1024 * 2048 + (size_t)nbase * 2048 + h * 64 + e;
    const float* kwr = kw + h * 1024 + nbase;

    float m = -1e30f, l = 0.f, s = 0.f;
    #pragma unroll 4
    for (int i = 0; i < 64; ++i) {
        const float kval = h2f(kp[(size_t)i * 2048]);
        const float x    = kval * kwr[i] * 0.125f;
        const float nm   = fmaxf(m, x);
        const float c    = __expf(m - nm);
        const float ex   = __expf(x - nm);
        l = l * c + ex;
        s = s * c + ex * kval;
        m = nm;
    }
    __shared__ float sm[3][256];
    sm[0][t] = m; sm[1][t] = l; sm[2][t] = s;
    __syncthreads();
    if (t < 64) {
        #pragma unroll
        for (int ww = 1; ww < 4; ++ww) {
            const float m2 = sm[0][ww * 64 + e];
            const float l2 = sm[1][ww * 64 + e];
            const float s2 = sm[2][ww * 64 + e];
            const float nm = fmaxf(m, m2);
            const float c1 = __expf(m - nm);
            const float c2 = __expf(m2 - nm);
            l = l * c1 + l2 * c2;
            s = s * c1 + s2 * c2;
            m = nm;
        }
        const int o = blk * 64 + e;
        pm[o] = m; pl[o] = l; ps[o] = s;
    }
}

__global__ __launch_bounds__(64) void attn_merge(
    const float* __restrict__ pm, const float* __restrict__ pl,
    const float* __restrict__ ps, float* __restrict__ gk)
{
    const int bh = blockIdx.x, e = threadIdx.x;
    const int b = bh >> 4, h = bh & 15;
    int o = bh * 4 * 64 + e;
    float m = pm[o], l = pl[o], s = ps[o];
    #pragma unroll
    for (int qt = 1; qt < 4; ++qt) {
        o += 64;
        const float m2 = pm[o], l2 = pl[o], s2 = ps[o];
        const float nm = fmaxf(m, m2);
        const float c1 = __expf(m - nm);
        const float c2 = __expf(m2 - nm);
        l = l * c1 + l2 * c2;
        s = s * c1 + s2 * c2;
        m = nm;
    }
    gk[(size_t)b * DM + h * 64 + e] = s / l;
}

// ---------------------------------------------------------------------------
// v-scale: vq[m][d] = fp16( v16[m][d] * gk[batch][d] ).
// ---------------------------------------------------------------------------
__global__ __launch_bounds__(256) void vscale_f16(
    const unsigned short* __restrict__ kv, const float* __restrict__ gk,
    unsigned short* __restrict__ vq)
{
    const int m = blockIdx.x;
    const int t = threadIdx.x;
    const int b = m >> 10;
    const ushort4 v4 = *(const ushort4*)(kv + (size_t)m * 2048 + 1024 + t * 4);
    const float4  s4 = *(const float4*)(gk + b * DM + t * 4);
    ushort4 o;
    o.x = f2h(h2f(v4.x) * s4.x);
    o.y = f2h(h2f(v4.y) * s4.y);
    o.z = f2h(h2f(v4.z) * s4.z);
    o.w = f2h(h2f(v4.w) * s4.w);
    *(ushort4*)(vq + (size_t)m * DM + t * 4) = o;
}

// ---------------------------------------------------------------------------
// fp16 MFMA GEMM: 256 thr = 4 waves (2x2), block tile 128x128
// (LIN1ACT: 128 rows x 64 output cols; wn=0 a-half, wn=1 g-half).
// Wave 64x64: acc 4x4 f32x4 = 64 AGPR -> 3 blocks/CU.
// A: global_load_lds, 2x16KB dbuf, XOR-swizzled rows.
// B: fragment-linear swizzled weights, coalesced direct-to-reg, reg dbuf.
// OUTM: 0 fp16 out, 2 fp32 out + residual.
// ---------------------------------------------------------------------------
template <bool LIN1ACT, int OUTM>
__global__ __launch_bounds__(256, 3) void fgemm(
    const unsigned short* __restrict__ A,
    const unsigned short* __restrict__ Bsw,
    const float* __restrict__ bias,
    const float* __restrict__ residual,
    float* __restrict__ Cf, unsigned short* __restrict__ Cq,
    int K, int lda, int ldc)
{
    __shared__ __align__(16) char lds[32768];   // 2x16KB A stages / 16KB xch

    const int t  = threadIdx.x;
    const int m0 = blockIdx.y * 128;
    const int n0 = blockIdx.x * (LIN1ACT ? 64 : 128);
    const int L  = t & 63, w = t >> 6;
    const int wm = w >> 1, wn = w & 1;
    const int fr = L & 15, q = L >> 4;
    const int KT = K >> 5;

    // A staging: 1024 chunks/stage, 4 per thread; c = t + j*256,
    // row = c>>3 (0..127), chunk-in-row = (c&7)^(row&7).
    const int arow = t >> 3;
    const int ach  = (t & 7) ^ (arow & 7);
    const unsigned short* pA0 = A + (size_t)(m0 + arow) * lda + ach * 8;
    const int ldst0 = t * 16;

    // B fragment-linear base for this wave's 64-col slice.
    const int bcol0 = LIN1ACT ? ((wn ? FFH : 0) + n0) : (n0 + wn * 64);
    const unsigned short* pB = Bsw + (size_t)(bcol0 >> 4) * KT * 512 + L * 8;

    int aoff[4];
    #pragma unroll
    for (int mi = 0; mi < 4; ++mi) {
        const int row = wm * 64 + mi * 16 + fr;
        aoff[mi] = row * 128 + ((q ^ (row & 7)) * 16);
    }

    f32x4 acc[4][4];
    #pragma unroll
    for (int i = 0; i < 4; ++i)
        #pragma unroll
        for (int j = 0; j < 4; ++j) acc[i][j] = (f32x4){0.f, 0.f, 0.f, 0.f};

    // prologue: stage 0 into buf0, B ktile 0 into b0
    #pragma unroll
    for (int j = 0; j < 4; ++j)
        gl2lds16(pA0 + (size_t)j * 32 * lda, lds + ldst0 + j * 4096);
    f16x8 b0[4], b1[4];
    #pragma unroll
    for (int ni = 0; ni < 4; ++ni)
        b0[ni] = *(const f16x8*)(pB + (size_t)ni * KT * 512);
    __syncthreads();

    int p = 0;
    for (int k0 = 0; k0 < K; k0 += 64) {
        const int ktn  = k0 >> 5;
        const int kpre = (k0 + 64 < K) ? k0 + 64 : 0;
        #pragma unroll
        for (int j = 0; j < 4; ++j)
            gl2lds16(pA0 + (size_t)j * 32 * lda + kpre,
                     lds + (p ^ 1) * 16384 + ldst0 + j * 4096);
        #pragma unroll
        for (int ni = 0; ni < 4; ++ni)
            b1[ni] = *(const f16x8*)(pB + ((size_t)ni * KT + ktn + 1) * 512);

        f16x8 af[4];
        #pragma unroll
        for (int mi = 0; mi < 4; ++mi)
            af[mi] = *(const f16x8*)(lds + p * 16384 + aoff[mi]);
        #pragma unroll
        for (int mi = 0; mi < 4; ++mi)
            #pragma unroll
            for (int ni = 0; ni < 4; ++ni)
                acc[mi][ni] = __builtin_amdgcn_mfma_f32_16x16x32_f16(
                    af[mi], b0[ni], acc[mi][ni], 0, 0, 0);

        const int kt2 = (ktn + 2 < KT) ? ktn + 2 : 0;
        #pragma unroll
        for (int ni = 0; ni < 4; ++ni)
            b0[ni] = *(const f16x8*)(pB + ((size_t)ni * KT + kt2) * 512);

        #pragma unroll
        for (int mi = 0; mi < 4; ++mi)
            af[mi] = *(const f16x8*)(lds + p * 16384 + (aoff[mi] ^ 64));
        #pragma unroll
        for (int mi = 0; mi < 4; ++mi)
            #pragma unroll
            for (int ni = 0; ni < 4; ++ni)
                acc[mi][ni] = __builtin_amdgcn_mfma_f32_16x16x32_f16(
                    af[mi], b1[ni], acc[mi][ni], 0, 0, 0);

        __syncthreads();
        p ^= 1;
    }

    if (!LIN1ACT) {
        float bc[4];
        #pragma unroll
        for (int ni = 0; ni < 4; ++ni)
            bc[ni] = bias[n0 + wn * 64 + ni * 16 + fr];
        #pragma unroll
        for (int mi = 0; mi < 4; ++mi)
            #pragma unroll
            for (int ni = 0; ni < 4; ++ni) {
                const int gcol = n0 + wn * 64 + ni * 16 + fr;
                #pragma unroll
                for (int r = 0; r < 4; ++r) {
                    const int grow = m0 + wm * 64 + mi * 16 + q * 4 + r;
                    float v = acc[mi][ni][r] + bc[ni];
                    if (OUTM == 2) {
                        v += residual[(size_t)grow * ldc + gcol];
                        Cf[(size_t)grow * ldc + gcol] = v;
                    } else {
                        Cq[(size_t)grow * ldc + gcol] = f2h(v);
                    }
                }
            }
    } else {
        unsigned short* xch = (unsigned short*)lds;   // [128][64] fp16 = 16KB
        if (wn == 1) {
            #pragma unroll
            for (int mi = 0; mi < 4; ++mi)
                #pragma unroll
                for (int ni = 0; ni < 4; ++ni) {
                    const int col = ni * 16 + fr;
                    const float bg = bias[FFH + n0 + col];
                    #pragma unroll
                    for (int r = 0; r < 4; ++r) {
                        const int row = wm * 64 + mi * 16 + q * 4 + r;
                        xch[row * 64 + col] =
                            f2h(fmaxf(acc[mi][ni][r] + bg, 0.f));
                    }
                }
        }
        __syncthreads();
        if (wn == 0) {
            #pragma unroll
            for (int mi = 0; mi < 4; ++mi)
                #pragma unroll
                for (int ni = 0; ni < 4; ++ni) {
                    const int col = ni * 16 + fr;
                    const float ba = bias[n0 + col];
                    #pragma unroll
                    for (int r = 0; r < 4; ++r) {
                        const int row = wm * 64 + mi * 16 + q * 4 + r;
                        const float a = acc[mi][ni][r] + ba;
                        const float o = a * h2f(xch[row * 64 + col]);
                        Cq[(size_t)(m0 + row) * FFH + n0 + col] = f2h(o);
                    }
                }
        }
    }
}

// ---------------------------------------------------------------------------
extern "C" void kernel_launch(void* const* d_in, const int* in_sizes, int n_in,
                              void* d_out, int out_size, void* d_ws, size_t ws_size,
                              hipStream_t stream)
{
    const float* hidden = (const float*)d_in[0];
    const float* qkv_w  = (const float*)d_in[2];
    const float* qkv_b  = (const float*)d_in[3];
    const float* out_w  = (const float*)d_in[4];
    const float* out_b  = (const float*)d_in[5];
    const float* key_w  = (const float*)d_in[7];
    const float* n1g    = (const float*)d_in[8];
    const float* n1b    = (const float*)d_in[9];
    const float* n2g    = (const float*)d_in[10];
    const float* n2b    = (const float*)d_in[11];
    const float* l1w    = (const float*)d_in[12];
    const float* l1b    = (const float*)d_in[13];
    const float* l2w    = (const float*)d_in[14];
    const float* l2b    = (const float*)d_in[15];
    float* out = (float*)d_out;
    char*  wsb = (char*)d_ws;

    const size_t MB = 1u << 20;
    unsigned short* h16    = (unsigned short*)wsb;               // 16 MB
    unsigned short* kv16   = (unsigned short*)(wsb + 16 * MB);   // 32 MB
    unsigned short* act16  = (unsigned short*)(wsb + 16 * MB);   // overlay
    unsigned short* vq     = (unsigned short*)(wsb + 48 * MB);   // 16 MB
    unsigned short* wkv_sw = (unsigned short*)(wsb + 64 * MB);   // 4 MB
    unsigned short* wo_sw  = (unsigned short*)(wsb + 68 * MB);   // 2 MB
    unsigned short* l1_sw  = (unsigned short*)(wsb + 70 * MB);   // 8 MB
    unsigned short* l2_sw  = (unsigned short*)(wsb + 78 * MB);   // 4 MB
    float*          gk     = (float*)(wsb + 82 * MB);            // 32 KB
    float*          pm     = (float*)(wsb + 83 * MB);            // 128 KB
    float*          pl     = (float*)(wsb + 83 * MB + 131072);
    float*          ps     = (float*)(wsb + 83 * MB + 262144);

    // 0. weights -> fp16 fragment-linear layout
    wcast_sw<<<4608, 256, 0, stream>>>(
        qkv_w + (size_t)DM * DM, out_w, l1w, l2w,
        wkv_sw, wo_sw, l1_sw, l2_sw);

    // 1. h1 = LN1(hidden) -> fp16
    ln_f16<<<M_TOT, 256, 0, stream>>>(hidden, n1g, n1b, h16);

    // 2. kv16 = fp16( h1 @ Wkv^T + b )  (ldc 2048), 1024 blocks
    fgemm<false, 0><<<dim3(16, 64), 256, 0, stream>>>(
        h16, wkv_sw, qkv_b + DM, nullptr, nullptr, kv16, 1024, 1024, 2048);

    // 3. global_key (partial + merge)
    attn_part<<<512, 256, 0, stream>>>(kv16, key_w, pm, pl, ps);
    attn_merge<<<128, 64, 0, stream>>>(pm, pl, ps, gk);

    // 4. vq = fp16(v * gk)
    vscale_f16<<<M_TOT, 256, 0, stream>>>(kv16, gk, vq);

    // 5. hidden2 = hidden + vq @ out_w^T + out_b -> d_out, 512 blocks
    fgemm<false, 2><<<dim3(8, 64), 256, 0, stream>>>(
        vq, wo_sw, out_b, hidden, out, nullptr, 1024, 1024, 1024);

    // 6. h2 = LN2(hidden2) -> fp16
    ln_f16<<<M_TOT, 256, 0, stream>>>(out, n2g, n2b, h16);

    // 7. act16 = fp16( (h2@W_a^T+b_a) * relu(h2@W_g^T+b_g) ), 2048 blocks
    fgemm<true, 0><<<dim3(32, 64), 256, 0, stream>>>(
        h16, l1_sw, l1b, nullptr, nullptr, act16, 1024, 1024, 0);

    // 8. out = hidden2 + act @ l2w^T + l2b (in-place residual), 512 blocks
    fgemm<false, 2><<<dim3(8, 64), 256, 0, stream>>>(
        act16, l2_sw, l2b, out, out, nullptr, 2048, 2048, 1024);
}